// Round 3
// baseline (162.298 us; speedup 1.0000x reference)
//
#include <hip/hip_runtime.h>
#include <hip/hip_bf16.h>

// Problem constants
#define B_ROWS 4096
#define NN     8192
#define DD     128
#define CSPLIT 16           // column splits (blocks per row-group)
#define NSPLIT (CSPLIT * 2) // wn adds another factor of 2
#define TSTEPS 4            // 256 pair-cols per block / 64 per t-step

typedef __attribute__((ext_vector_type(8))) short s8v;   // 8 bf16 (4 VGPR)
typedef __attribute__((ext_vector_type(4))) float f4v;   // 4 f32
typedef __attribute__((ext_vector_type(2))) float f2v;

static constexpr float SCALE_H = 1.6986436f;      // sqrt(2*log2(e)); folds /TEMP and log2e into the matmul
static constexpr float SCALE2  = 2.8853900818f;   // 2*log2(e)
static constexpr float LN2     = 0.6931471805599453f;
static constexpr float MASKVAL = -3.0e38f;
static constexpr float MINIT   = -1.0e30f;

// ---- kernel 1: f32 -> scaled bf16 concat(h_i, h_j) ----
__global__ void prep_kernel(const float* __restrict__ hi, const float* __restrict__ hj,
                            __hip_bfloat16* __restrict__ hb) {
    int t = blockIdx.x * 256 + threadIdx.x;     // 131072 threads, 8 elems each
    int base = t * 8;
    const float* src = (base < B_ROWS * DD) ? (hi + base) : (hj + (base - B_ROWS * DD));
    f4v a = ((const f4v*)src)[0];
    f4v b = ((const f4v*)src)[1];
    union { s8v v; __hip_bfloat16 h[8]; } u;
    u.h[0] = __float2bfloat16(a[0] * SCALE_H);
    u.h[1] = __float2bfloat16(a[1] * SCALE_H);
    u.h[2] = __float2bfloat16(a[2] * SCALE_H);
    u.h[3] = __float2bfloat16(a[3] * SCALE_H);
    u.h[4] = __float2bfloat16(b[0] * SCALE_H);
    u.h[5] = __float2bfloat16(b[1] * SCALE_H);
    u.h[6] = __float2bfloat16(b[2] * SCALE_H);
    u.h[7] = __float2bfloat16(b[3] * SCALE_H);
    ((s8v*)hb)[t] = u.v;
}

// ---- kernel 2: pos2[i] = 2*log2e * dot_f32(h_i[i], h_j[i]) ----
__global__ void pos_kernel(const float* __restrict__ hi, const float* __restrict__ hj,
                           float* __restrict__ pos2) {
    int w = threadIdx.x >> 6, l = threadIdx.x & 63;
    int row = blockIdx.x * 4 + w;
    f2v a = ((const f2v*)(hi + (size_t)row * DD))[l];
    f2v b = ((const f2v*)(hj + (size_t)row * DD))[l];
    float d = a[0] * b[0] + a[1] * b[1];
    #pragma unroll
    for (int off = 32; off; off >>= 1) d += __shfl_xor(d, off, 64);
    if (l == 0) pos2[row] = SCALE2 * d;
}

// ---- kernel 3: fused sim*S2 + masked online logsumexp (log2 domain) ----
// Block: 256 thr = 4 waves. Wave (wm,wn). Rows: {r0..r0+15} U {+B} (fm picks half).
// Cols per t-step: {pc0..pc0+31} U {+B}. One S load feeds 4 sim elements.
// t-loop fully unrolled; S prefetched one step ahead (rolling double-buffer).
__global__ __launch_bounds__(256, 4)
void main_kernel(const __hip_bfloat16* __restrict__ hb, const float* __restrict__ S,
                 float* __restrict__ msplit, float* __restrict__ ssplit) {
    const int tid = threadIdx.x;
    const int l  = tid & 63;
    const int w  = tid >> 6;
    const int wm = w >> 1, wn = w & 1;
    const int rb = blockIdx.x & 127;
    const int cs = blockIdx.x >> 7;
    const int r0 = rb * 32 + wm * 16;    // wave row base (first half)
    const int c0 = cs * 256;             // pair-column range for this split
    const int lc = l & 15;               // frag row/col within 16
    const int lk = l >> 4;               // k-group

    const s8v* hb8 = (const s8v*)hb;     // 16 x s8v per row of 128 bf16

    // A fragments, hoisted for the entire sweep
    s8v afr[2][4];
    #pragma unroll
    for (int fm = 0; fm < 2; fm++) {
        int ar = r0 + lc + fm * B_ROWS;
        #pragma unroll
        for (int kk = 0; kk < 4; kk++)
            afr[fm][kk] = hb8[ar * 16 + kk * 4 + lk];
    }

    float m[2][4], ssum[2][4];
    #pragma unroll
    for (int fm = 0; fm < 2; fm++)
        #pragma unroll
        for (int r = 0; r < 4; r++) { m[fm][r] = MINIT; ssum[fm][r] = 0.f; }

    const int srowbase = r0 + lk * 4;    // S row for (r)

    // rolling S prefetch: spre[buf][r][fp]
    float spre[2][4][2];
    {
        const int pc0 = c0 + wn * 32;
        #pragma unroll
        for (int r = 0; r < 4; r++)
            #pragma unroll
            for (int fp = 0; fp < 2; fp++)
                spre[0][r][fp] = S[(size_t)(srowbase + r) * B_ROWS + pc0 + fp * 16 + lc];
    }

    #pragma unroll
    for (int t = 0; t < TSTEPS; t++) {
        const int pc0 = c0 + t * 64 + wn * 32;

        // prefetch next t-step's S values (independent; hides L3/HBM latency)
        if (t < TSTEPS - 1) {
            const int pn = pc0 + 64;
            #pragma unroll
            for (int r = 0; r < 4; r++)
                #pragma unroll
                for (int fp = 0; fp < 2; fp++)
                    spre[(t + 1) & 1][r][fp] = S[(size_t)(srowbase + r) * B_ROWS + pn + fp * 16 + lc];
        }

        f4v acc[2][4];
        #pragma unroll
        for (int fm = 0; fm < 2; fm++)
            #pragma unroll
            for (int fn = 0; fn < 4; fn++) acc[fm][fn] = f4v{0.f, 0.f, 0.f, 0.f};

        #pragma unroll
        for (int kk = 0; kk < 4; kk++) {
            s8v bfr[4];
            #pragma unroll
            for (int fn = 0; fn < 4; fn++) {
                int bc = pc0 + (fn & 1) * 16 + lc + ((fn >> 1) ? B_ROWS : 0);
                bfr[fn] = hb8[bc * 16 + kk * 4 + lk];
            }
            #pragma unroll
            for (int fm = 0; fm < 2; fm++)
                #pragma unroll
                for (int fn = 0; fn < 4; fn++)
                    acc[fm][fn] = __builtin_amdgcn_mfma_f32_16x16x32_bf16(
                        afr[fm][kk], bfr[fn], acc[fm][fn], 0, 0, 0);
        }

        // epilogue: scale by (1 - S^2), mask, batched branchless online lse
        #pragma unroll
        for (int r = 0; r < 4; r++) {
            const int srow = srowbase + r;
            const float Sv0 = spre[t & 1][r][0];
            const float Sv1 = spre[t & 1][r][1];
            const float s20 = 1.f - Sv0 * Sv0;
            const float s21 = 1.f - Sv1 * Sv1;
            const bool msk0 = (pc0 + lc == srow);        // covers j==n and j==(n+B)%N
            const bool msk1 = (pc0 + 16 + lc == srow);
            #pragma unroll
            for (int fm = 0; fm < 2; fm++) {
                float v00 = msk0 ? MASKVAL : acc[fm][0][r] * s20;
                float v01 = msk1 ? MASKVAL : acc[fm][1][r] * s21;
                float v10 = msk0 ? MASKVAL : acc[fm][2][r] * s20;
                float v11 = msk1 ? MASKVAL : acc[fm][3][r] * s21;
                float bm = fmaxf(fmaxf(v00, v01), fmaxf(v10, v11));
                float mo = m[fm][r];
                float nm = fmaxf(mo, bm);
                ssum[fm][r] = ssum[fm][r] * exp2f(mo - nm)
                            + ((exp2f(v00 - nm) + exp2f(v01 - nm))
                             + (exp2f(v10 - nm) + exp2f(v11 - nm)));
                m[fm][r] = nm;
            }
        }
    }

    // reduce (m,s) across the 16 lanes holding the same row, write per-split state
    #pragma unroll
    for (int fm = 0; fm < 2; fm++) {
        #pragma unroll
        for (int r = 0; r < 4; r++) {
            float mm = m[fm][r], ss = ssum[fm][r];
            #pragma unroll
            for (int off = 1; off < 16; off <<= 1) {
                float mo = __shfl_xor(mm, off, 64);
                float so = __shfl_xor(ss, off, 64);
                float nm = fmaxf(mm, mo);
                ss = ss * exp2f(mm - nm) + so * exp2f(mo - nm);
                mm = nm;
            }
            if (lc == 0) {
                int gr = srowbase + r + fm * B_ROWS;
                int sp = cs * 2 + wn;
                msplit[sp * NN + gr] = mm;
                ssplit[sp * NN + gr] = ss;
            }
        }
    }
}

// ---- kernel 4a: per-row split merge + lse, block partial sums (parallel) ----
__global__ __launch_bounds__(256)
void reduce_kernel(const float* __restrict__ msplit, const float* __restrict__ ssplit,
                   const float* __restrict__ pos2, float* __restrict__ partial) {
    __shared__ float red[256];
    const int n = blockIdx.x * 256 + threadIdx.x;   // n < 8192
    float p = pos2[n & (B_ROWS - 1)];
    float M = p, Ssum = 1.f;                        // pos logit seeds the lse
    #pragma unroll
    for (int sp = 0; sp < NSPLIT; sp++) {
        float mo = msplit[sp * NN + n];
        float so = ssplit[sp * NN + n];
        float nm = fmaxf(M, mo);
        Ssum = Ssum * exp2f(M - nm) + so * exp2f(mo - nm);
        M = nm;
    }
    red[threadIdx.x] = (M + log2f(Ssum)) - p;       // log2 units
    __syncthreads();
    for (int st = 128; st; st >>= 1) {
        if (threadIdx.x < st) red[threadIdx.x] += red[threadIdx.x + st];
        __syncthreads();
    }
    if (threadIdx.x == 0) partial[blockIdx.x] = red[0];
}

// ---- kernel 4b: deterministic final sum over 32 partials ----
__global__ void final_kernel(const float* __restrict__ partial, float* __restrict__ out) {
    if (threadIdx.x == 0) {
        float s = 0.f;
        #pragma unroll
        for (int i = 0; i < 32; i++) s += partial[i];
        out[0] = s * (LN2 / (float)NN);
    }
}

extern "C" void kernel_launch(void* const* d_in, const int* in_sizes, int n_in,
                              void* d_out, int out_size, void* d_ws, size_t ws_size,
                              hipStream_t stream) {
    (void)in_sizes; (void)n_in; (void)out_size; (void)ws_size;
    const float* hi = (const float*)d_in[0];
    const float* hj = (const float*)d_in[1];
    const float* S  = (const float*)d_in[2];

    char* ws = (char*)d_ws;
    __hip_bfloat16* hb = (__hip_bfloat16*)ws;                        // 2 MB
    float* pos2   = (float*)(ws + 2097152);                          // 16 KB
    float* msplit = (float*)(ws + 2097152 + 16384);                  // 1 MB (32 splits)
    float* ssplit = (float*)(ws + 2097152 + 16384 + 1048576);        // 1 MB
    float* partial= (float*)(ws + 2097152 + 16384 + 2 * 1048576);    // 128 B

    prep_kernel<<<512, 256, 0, stream>>>(hi, hj, hb);
    pos_kernel<<<1024, 256, 0, stream>>>(hi, hj, pos2);
    main_kernel<<<2048, 256, 0, stream>>>(hb, S, msplit, ssplit);
    reduce_kernel<<<32, 256, 0, stream>>>(msplit, ssplit, pos2, partial);
    final_kernel<<<1, 64, 0, stream>>>(partial, (float*)d_out);
}

// Round 4
// 88.470 us; speedup vs baseline: 1.8345x; 1.8345x over previous
//
#include <hip/hip_runtime.h>
#include <hip/hip_bf16.h>

// Problem constants
#define B_ROWS 4096
#define NN     8192
#define DD     128
#define CSPLIT 16           // column splits (blocks per row-group)
#define NSPLIT (CSPLIT * 2) // wn adds another factor of 2
#define TSTEPS 8            // 128 pair-cols per wn / 16 per t-step

typedef __attribute__((ext_vector_type(8))) short s8v;   // 8 bf16 (4 VGPR)
typedef __attribute__((ext_vector_type(4))) float f4v;   // 4 f32
typedef __attribute__((ext_vector_type(2))) float f2v;

static constexpr float SCALE_H = 1.6986436f;      // sqrt(2*log2(e)); folds /TEMP and log2e into the matmul
static constexpr float SCALE2  = 2.8853900818f;   // 2*log2(e)
static constexpr float LN2     = 0.6931471805599453f;
static constexpr float MASKVAL = -3.0e38f;
static constexpr float MINIT   = -1.0e30f;

__device__ __forceinline__ float fast_exp2(float x) {
#if __has_builtin(__builtin_amdgcn_exp2f)
    return __builtin_amdgcn_exp2f(x);      // bare v_exp_f32
#else
    return exp2f(x);
#endif
}

// ---- kernel 1: f32 -> scaled bf16 concat(h_i, h_j) ----
__global__ void prep_kernel(const float* __restrict__ hi, const float* __restrict__ hj,
                            __hip_bfloat16* __restrict__ hb) {
    int t = blockIdx.x * 256 + threadIdx.x;     // 131072 threads, 8 elems each
    int base = t * 8;
    const float* src = (base < B_ROWS * DD) ? (hi + base) : (hj + (base - B_ROWS * DD));
    f4v a = ((const f4v*)src)[0];
    f4v b = ((const f4v*)src)[1];
    union { s8v v; __hip_bfloat16 h[8]; } u;
    u.h[0] = __float2bfloat16(a[0] * SCALE_H);
    u.h[1] = __float2bfloat16(a[1] * SCALE_H);
    u.h[2] = __float2bfloat16(a[2] * SCALE_H);
    u.h[3] = __float2bfloat16(a[3] * SCALE_H);
    u.h[4] = __float2bfloat16(b[0] * SCALE_H);
    u.h[5] = __float2bfloat16(b[1] * SCALE_H);
    u.h[6] = __float2bfloat16(b[2] * SCALE_H);
    u.h[7] = __float2bfloat16(b[3] * SCALE_H);
    ((s8v*)hb)[t] = u.v;
}

// ---- kernel 2: pos2[i] = 2*log2e * dot_f32(h_i[i], h_j[i]) ----
__global__ void pos_kernel(const float* __restrict__ hi, const float* __restrict__ hj,
                           float* __restrict__ pos2) {
    int w = threadIdx.x >> 6, l = threadIdx.x & 63;
    int row = blockIdx.x * 4 + w;
    f2v a = ((const f2v*)(hi + (size_t)row * DD))[l];
    f2v b = ((const f2v*)(hj + (size_t)row * DD))[l];
    float d = a[0] * b[0] + a[1] * b[1];
    #pragma unroll
    for (int off = 32; off; off >>= 1) d += __shfl_xor(d, off, 64);
    if (l == 0) pos2[row] = SCALE2 * d;
}

// ---- kernel 3: fused sim*S2 + masked online logsumexp (log2 domain) ----
// Block: 256 thr = 4 waves, wave (wm,wn). Rows: {r0..r0+15} U {+B} (fm).
// Per t-step: 16 pair-cols {pc..pc+15} U {+B} (fh). One S value feeds 4 elems.
// B-frags and S double-buffered in NAMED registers (static indices only),
// prefetched one t-step ahead.
__global__ __launch_bounds__(256, 2)
void main_kernel(const __hip_bfloat16* __restrict__ hb, const float* __restrict__ S,
                 float* __restrict__ msplit, float* __restrict__ ssplit) {
    const int tid = threadIdx.x;
    const int l  = tid & 63;
    const int w  = tid >> 6;
    const int wm = w >> 1, wn = w & 1;
    const int rb = blockIdx.x & 127;
    const int cs = blockIdx.x >> 7;
    const int r0 = rb * 32 + wm * 16;    // wave row base (first half)
    const int c0 = cs * 256;             // 256 pair-cols per block
    const int lc = l & 15;               // frag row/col within 16
    const int lk = l >> 4;               // k-group

    const s8v* hb8 = (const s8v*)hb;     // 16 x s8v per row of 128 bf16

    // A fragments, hoisted for the entire sweep
    s8v afr[2][4];
    #pragma unroll
    for (int fm = 0; fm < 2; fm++) {
        int ar = r0 + lc + fm * B_ROWS;
        #pragma unroll
        for (int kk = 0; kk < 4; kk++)
            afr[fm][kk] = hb8[ar * 16 + kk * 4 + lk];
    }

    float m[2][4], ssum[2][4];
    #pragma unroll
    for (int fm = 0; fm < 2; fm++)
        #pragma unroll
        for (int r = 0; r < 4; r++) { m[fm][r] = MINIT; ssum[fm][r] = 0.f; }

    const int srowbase = r0 + lk * 4;    // S row for (r)

#define PCOL(T) (c0 + (T) * 32 + wn * 16)

#define LOADB(BF, T) do {                                                   \
    const int _pc = PCOL(T);                                                \
    _Pragma("unroll")                                                       \
    for (int fh = 0; fh < 2; fh++) {                                        \
        _Pragma("unroll")                                                   \
        for (int kk = 0; kk < 4; kk++)                                      \
            BF[fh][kk] = hb8[(_pc + lc + fh * B_ROWS) * 16 + kk * 4 + lk];  \
    }                                                                       \
} while (0)

#define LOADS(SP, T) do {                                                   \
    const int _pc = PCOL(T);                                                \
    _Pragma("unroll")                                                       \
    for (int r = 0; r < 4; r++)                                             \
        SP[r] = S[(srowbase + r) * B_ROWS + _pc + lc];                      \
} while (0)

#define COMPUTE(BF, SP, T) do {                                             \
    f4v acc[2][2];                                                          \
    _Pragma("unroll")                                                       \
    for (int fm = 0; fm < 2; fm++)                                          \
        _Pragma("unroll")                                                   \
        for (int fh = 0; fh < 2; fh++) acc[fm][fh] = f4v{0.f, 0.f, 0.f, 0.f};\
    _Pragma("unroll")                                                       \
    for (int kk = 0; kk < 4; kk++)                                          \
        _Pragma("unroll")                                                   \
        for (int fm = 0; fm < 2; fm++)                                      \
            _Pragma("unroll")                                               \
            for (int fh = 0; fh < 2; fh++)                                  \
                acc[fm][fh] = __builtin_amdgcn_mfma_f32_16x16x32_bf16(      \
                    afr[fm][kk], BF[fh][kk], acc[fm][fh], 0, 0, 0);         \
    const int _pc = PCOL(T);                                                \
    _Pragma("unroll")                                                       \
    for (int r = 0; r < 4; r++) {                                           \
        const bool msk = (_pc + lc == srowbase + r);                        \
        const float Sv = SP[r];                                             \
        const float s2 = 1.f - Sv * Sv;                                     \
        _Pragma("unroll")                                                   \
        for (int fm = 0; fm < 2; fm++) {                                    \
            float v0 = msk ? MASKVAL : acc[fm][0][r] * s2;                  \
            float v1 = msk ? MASKVAL : acc[fm][1][r] * s2;                  \
            float mo = m[fm][r];                                            \
            float nm = fmaxf(mo, fmaxf(v0, v1));                            \
            ssum[fm][r] = ssum[fm][r] * fast_exp2(mo - nm)                  \
                        + fast_exp2(v0 - nm) + fast_exp2(v1 - nm);          \
            m[fm][r] = nm;                                                  \
        }                                                                   \
    }                                                                       \
} while (0)

    // named ping-pong buffers (static indexing only)
    s8v bA[2][4], bB[2][4];
    float sA[4], sB[4];

    LOADB(bA, 0);
    LOADS(sA, 0);
    for (int tt = 0; tt < TSTEPS; tt += 2) {
        LOADB(bB, tt + 1);
        LOADS(sB, tt + 1);
        COMPUTE(bA, sA, tt);
        if (tt + 2 < TSTEPS) {
            LOADB(bA, tt + 2);
            LOADS(sA, tt + 2);
        }
        COMPUTE(bB, sB, tt + 1);
    }

#undef PCOL
#undef LOADB
#undef LOADS
#undef COMPUTE

    // reduce (m,s) across the 16 lanes holding the same row, write per-split state
    #pragma unroll
    for (int fm = 0; fm < 2; fm++) {
        #pragma unroll
        for (int r = 0; r < 4; r++) {
            float mm = m[fm][r], ss = ssum[fm][r];
            #pragma unroll
            for (int off = 1; off < 16; off <<= 1) {
                float mo = __shfl_xor(mm, off, 64);
                float so = __shfl_xor(ss, off, 64);
                float nm = fmaxf(mm, mo);
                ss = ss * fast_exp2(mm - nm) + so * fast_exp2(mo - nm);
                mm = nm;
            }
            if (lc == 0) {
                int gr = srowbase + r + fm * B_ROWS;
                int sp = cs * 2 + wn;
                msplit[sp * NN + gr] = mm;
                ssplit[sp * NN + gr] = ss;
            }
        }
    }
}

// ---- kernel 4a: per-row split merge + lse, block partial sums (parallel) ----
__global__ __launch_bounds__(256)
void reduce_kernel(const float* __restrict__ msplit, const float* __restrict__ ssplit,
                   const float* __restrict__ pos2, float* __restrict__ partial) {
    __shared__ float red[256];
    const int n = blockIdx.x * 256 + threadIdx.x;   // n < 8192
    float p = pos2[n & (B_ROWS - 1)];
    float M = p, Ssum = 1.f;                        // pos logit seeds the lse
    #pragma unroll
    for (int sp = 0; sp < NSPLIT; sp++) {
        float mo = msplit[sp * NN + n];
        float so = ssplit[sp * NN + n];
        float nm = fmaxf(M, mo);
        Ssum = Ssum * fast_exp2(M - nm) + so * fast_exp2(mo - nm);
        M = nm;
    }
    red[threadIdx.x] = (M + log2f(Ssum)) - p;       // log2 units
    __syncthreads();
    for (int st = 128; st; st >>= 1) {
        if (threadIdx.x < st) red[threadIdx.x] += red[threadIdx.x + st];
        __syncthreads();
    }
    if (threadIdx.x == 0) partial[blockIdx.x] = red[0];
}

// ---- kernel 4b: deterministic final sum over 32 partials ----
__global__ void final_kernel(const float* __restrict__ partial, float* __restrict__ out) {
    if (threadIdx.x == 0) {
        float s = 0.f;
        #pragma unroll
        for (int i = 0; i < 32; i++) s += partial[i];
        out[0] = s * (LN2 / (float)NN);
    }
}

extern "C" void kernel_launch(void* const* d_in, const int* in_sizes, int n_in,
                              void* d_out, int out_size, void* d_ws, size_t ws_size,
                              hipStream_t stream) {
    (void)in_sizes; (void)n_in; (void)out_size; (void)ws_size;
    const float* hi = (const float*)d_in[0];
    const float* hj = (const float*)d_in[1];
    const float* S  = (const float*)d_in[2];

    char* ws = (char*)d_ws;
    __hip_bfloat16* hb = (__hip_bfloat16*)ws;                        // 2 MB
    float* pos2   = (float*)(ws + 2097152);                          // 16 KB
    float* msplit = (float*)(ws + 2097152 + 16384);                  // 1 MB (32 splits)
    float* ssplit = (float*)(ws + 2097152 + 16384 + 1048576);        // 1 MB
    float* partial= (float*)(ws + 2097152 + 16384 + 2 * 1048576);    // 128 B

    prep_kernel<<<512, 256, 0, stream>>>(hi, hj, hb);
    pos_kernel<<<1024, 256, 0, stream>>>(hi, hj, pos2);
    main_kernel<<<2048, 256, 0, stream>>>(hb, S, msplit, ssplit);
    reduce_kernel<<<32, 256, 0, stream>>>(msplit, ssplit, pos2, partial);
    final_kernel<<<1, 64, 0, stream>>>(partial, (float*)d_out);
}